// Round 2
// baseline (517.959 us; speedup 1.0000x reference)
//
#include <hip/hip_runtime.h>

// ---------------------------------------------------------------------------
// PerWellMLPTransition on MI355X — f32, round 2
//
// zt1[b,i] = sum_{jp,k} w[b,jp]*hz[b,k]*G[jp,k,i] + sum_{jp} w[b,jp]*Gb[jp,i]
//   w[b] = [zt[b,:], ut[b,:]*dt[b]] (152);  G from WA/WB transposed to [jp][k][i].
//
// Round-2 changes (theory-only; no counters yet):
//  - 1-D gemm grid, ks = bid&7  -> each XCD owns one L2-resident G k-slice
//  - hz k-slice hoisted to registers (jp-invariant) -> GEMM VALU-bound, not LDS-bound
//  - double-buffered Gs, single barrier per jp
//  - bias contraction distributed across all 8 k-splits (19 jp each)
// ---------------------------------------------------------------------------

#define NB   4096
#define LAT  128
#define UD   24
#define HIDN 200
#define ZUD  152
#define JPD  152   // 128 + 24

// ws layout (in floats)
#define GT_OFF      0u          // [152][128][128] = 2,490,368
#define GB_OFF      2490368u    // [152][128]      = 19,456
#define HZ_OFF      2509824u    // [4096][128]     = 524,288
#define PART_OFF    3034112u    // [8][4096][128]  = 4,194,304
#define PART_STRIDE 524288u

// ---------- kernel 1: build transposed G + Gb ----------
__global__ __launch_bounds__(256)
void build_gt_kernel(const float* __restrict__ WA, const float* __restrict__ bA,
                     const float* __restrict__ WB, const float* __restrict__ bB,
                     float* __restrict__ Gt, float* __restrict__ Gb) {
  __shared__ float tile[128][129];   // [i][k], pad -> conflict-free column reads
  const int jp = blockIdx.x;         // 0..151
  const int t  = threadIdx.x;        // 256
  const bool isA = (jp < LAT);
  const float* __restrict__ src = isA ? WA : WB;
  const int mul = isA ? LAT : UD;
  const int sub = isA ? jp : (jp - LAT);
  for (int ib = 0; ib < 128; ib += 2) {
    const int i = ib + (t >> 7);
    const int k = t & 127;
    tile[i][k] = src[(size_t)(i * mul + sub) * 128 + k];   // coalesced over k
  }
  __syncthreads();
  float* __restrict__ dst = Gt + ((size_t)jp << 14);
  for (int kb = 0; kb < 128; kb += 2) {
    const int k = kb + (t >> 7);
    const int i = t & 127;
    dst[(k << 7) + i] = tile[i][k];                        // coalesced over i
  }
  if (t < 128) {
    const float* __restrict__ bsrc = isA ? bA : bB;
    Gb[(jp << 7) + t] = bsrc[t * mul + sub];
  }
}

// ---------- kernel 2: fused 3-layer encoder -> hz ----------
__global__ __launch_bounds__(256, 2)
void encoder_kernel(const float* __restrict__ zt, const float* __restrict__ dt,
                    const float* __restrict__ We1, const float* __restrict__ be1,
                    const float* __restrict__ We2, const float* __restrict__ be2,
                    const float* __restrict__ We3, const float* __restrict__ be3,
                    float* __restrict__ hz) {
  __shared__ float xs[8][132];
  __shared__ float h1[8][200];
  __shared__ float h2[8][200];
  const int t  = threadIdx.x;
  const int b0 = blockIdx.x * 8;

  for (int idx = t; idx < 8 * 129; idx += 256) {
    const int r = idx / 129, c = idx - r * 129;
    xs[r][c] = (c < LAT) ? zt[(size_t)(b0 + r) * LAT + c] : dt[b0 + r];
  }
  __syncthreads();

  // layer 1: thread t owns output o=t for all 8 rows (weights read once)
  if (t < HIDN) {
    const float* __restrict__ w = We1 + t * 129;
    float acc[8];
    const float bias = be1[t];
#pragma unroll
    for (int r = 0; r < 8; ++r) acc[r] = bias;
    for (int c = 0; c < 128; c += 4) {
      const float w0 = w[c], w1 = w[c + 1], w2 = w[c + 2], w3 = w[c + 3];
#pragma unroll
      for (int r = 0; r < 8; ++r) {
        const float4 xv = *(const float4*)(&xs[r][c]);
        acc[r] += xv.x * w0 + xv.y * w1 + xv.z * w2 + xv.w * w3;
      }
    }
    const float wl = w[128];
#pragma unroll
    for (int r = 0; r < 8; ++r) h1[r][t] = fmaxf(fmaf(xs[r][128], wl, acc[r]), 0.f);
  }
  __syncthreads();

  // layer 2
  if (t < HIDN) {
    const float* __restrict__ w = We2 + t * HIDN;
    float acc[8];
    const float bias = be2[t];
#pragma unroll
    for (int r = 0; r < 8; ++r) acc[r] = bias;
    for (int c = 0; c < HIDN; c += 4) {
      const float4 wv = *(const float4*)(w + c);
#pragma unroll
      for (int r = 0; r < 8; ++r) {
        const float4 hv = *(const float4*)(&h1[r][c]);
        acc[r] += hv.x * wv.x + hv.y * wv.y + hv.z * wv.z + hv.w * wv.w;
      }
    }
#pragma unroll
    for (int r = 0; r < 8; ++r) h2[r][t] = fmaxf(acc[r], 0.f);
  }
  __syncthreads();

  // layer 3 (no relu) -> hz
  if (t < LAT) {
    const float* __restrict__ w = We3 + t * HIDN;
    float acc[8];
    const float bias = be3[t];
#pragma unroll
    for (int r = 0; r < 8; ++r) acc[r] = bias;
    for (int c = 0; c < HIDN; c += 4) {
      const float4 wv = *(const float4*)(w + c);
#pragma unroll
      for (int r = 0; r < 8; ++r) {
        const float4 hv = *(const float4*)(&h2[r][c]);
        acc[r] += hv.x * wv.x + hv.y * wv.y + hv.z * wv.z + hv.w * wv.w;
      }
    }
#pragma unroll
    for (int r = 0; r < 8; ++r) hz[(size_t)(b0 + r) * LAT + t] = acc[r];
  }
}

// ---------- kernel 3: transition GEMM (rank-1 A-operand on the fly) ----------
#define ROWFMA(ACC, AV, GA, GB)                                           \
  { const float _a = (AV);                                                \
    ACC[0] = fmaf(_a, GA.x, ACC[0]); ACC[1] = fmaf(_a, GA.y, ACC[1]);     \
    ACC[2] = fmaf(_a, GA.z, ACC[2]); ACC[3] = fmaf(_a, GA.w, ACC[3]);     \
    ACC[4] = fmaf(_a, GB.x, ACC[4]); ACC[5] = fmaf(_a, GB.y, ACC[5]);     \
    ACC[6] = fmaf(_a, GB.z, ACC[6]); ACC[7] = fmaf(_a, GB.w, ACC[7]); }

// BM=64 rows, full N=128, K-slice of 16 per block. 512 blocks = 2/CU.
// Thread (tx,ty): cols c=tx*8, rows r=ty+16m (m=0..3). hz slice in VGPRs.
__global__ __launch_bounds__(256, 2)
void gemm_kernel(const float* __restrict__ zt, const float* __restrict__ dt,
                 const float* __restrict__ ut,
                 const float* __restrict__ Gt, const float* __restrict__ Gb,
                 const float* __restrict__ hz, float* __restrict__ part) {
  __shared__ float wtile[64][156];   // stride 156: 16B-aligned rows, 28-bank skew
  __shared__ float Gs[2][16][128];   // double-buffered G chunk
  const int t  = threadIdx.x;
  const int tx = t & 15, ty = t >> 4;
  const int bid = blockIdx.x;
  const int ks = bid & 7;            // XCD-aligned k-split (bid%8 == XCD heuristic)
  const int b0 = (bid >> 3) << 6;    // 64 rows per m-block
  const int k0 = ks << 4;
  const int c  = tx << 3;

  // stage w = [zt, ut*dt] (vectorized)
  for (int q = t; q < 2048; q += 256) {            // zt: 64 rows x 32 float4
    const int r = q >> 5, c4 = (q & 31) << 2;
    *(float4*)(&wtile[r][c4]) = *(const float4*)(zt + (((size_t)(b0 + r)) << 7) + c4);
  }
  for (int q = t; q < 384; q += 256) {             // ut*dt: 64 rows x 6 float4
    const int r = q / 6, u4 = (q - r * 6) << 2;
    float4 v = *(const float4*)(ut + (size_t)(b0 + r) * UD + u4);
    const float s = dt[b0 + r];
    v.x *= s; v.y *= s; v.z *= s; v.w *= s;
    *(float4*)(&wtile[r][LAT + u4]) = v;
  }

  // hz k-slice -> registers (jp-invariant; 4 KB block slice is L1-resident)
  float4 hzr[4][4];
#pragma unroll
  for (int m = 0; m < 4; ++m) {
    const float* __restrict__ hp = hz + (((size_t)(b0 + ty + (m << 4))) << 7) + k0;
#pragma unroll
    for (int kq = 0; kq < 4; ++kq) hzr[m][kq] = *(const float4*)(hp + (kq << 2));
  }

  float acc[4][8];
#pragma unroll
  for (int m = 0; m < 4; ++m)
#pragma unroll
    for (int i = 0; i < 8; ++i) acc[m][i] = 0.f;

  // prefetch first G chunk (16x128 = 2 float4/thread)
  const float* __restrict__ g0 = Gt + ((size_t)k0 << 7);
  float4 pf0 = *(const float4*)(g0 + (t << 2));
  float4 pf1 = *(const float4*)(g0 + (t << 2) + 1024);

  for (int jp = 0; jp < JPD; ++jp) {
    float* __restrict__ Gw = &Gs[jp & 1][0][0];
    *(float4*)(Gw + (t << 2))        = pf0;
    *(float4*)(Gw + (t << 2) + 1024) = pf1;
    __syncthreads();   // single barrier/iter: also orders reuse of buf (see note)
    if (jp + 1 < JPD) {
      const float* __restrict__ nx = Gt + (size_t)(jp + 1) * 16384 + ((size_t)k0 << 7);
      pf0 = *(const float4*)(nx + (t << 2));
      pf1 = *(const float4*)(nx + (t << 2) + 1024);
    }
    float wv[4];
#pragma unroll
    for (int m = 0; m < 4; ++m) wv[m] = wtile[ty + (m << 4)][jp];
    const float(* __restrict__ Gc)[128] = Gs[jp & 1];
#pragma unroll
    for (int kq = 0; kq < 4; ++kq) {
      const int kb = kq << 2;
      const float4 gA0 = *(const float4*)(&Gc[kb + 0][c]);
      const float4 gB0 = *(const float4*)(&Gc[kb + 0][c + 4]);
      const float4 gA1 = *(const float4*)(&Gc[kb + 1][c]);
      const float4 gB1 = *(const float4*)(&Gc[kb + 1][c + 4]);
      const float4 gA2 = *(const float4*)(&Gc[kb + 2][c]);
      const float4 gB2 = *(const float4*)(&Gc[kb + 2][c + 4]);
      const float4 gA3 = *(const float4*)(&Gc[kb + 3][c]);
      const float4 gB3 = *(const float4*)(&Gc[kb + 3][c + 4]);
#pragma unroll
      for (int m = 0; m < 4; ++m) {
        const float4 h = hzr[m][kq];
        float a;
        a = wv[m] * h.x; ROWFMA(acc[m], a, gA0, gB0);
        a = wv[m] * h.y; ROWFMA(acc[m], a, gA1, gB1);
        a = wv[m] * h.z; ROWFMA(acc[m], a, gA2, gB2);
        a = wv[m] * h.w; ROWFMA(acc[m], a, gA3, gB3);
      }
    }
  }

  // bias contraction: 19 jp per k-split (balanced across XCDs)
  const int blo = ks * 19, bhi = blo + 19;
  for (int jp = blo; jp < bhi; ++jp) {
    float wv[4];
#pragma unroll
    for (int m = 0; m < 4; ++m) wv[m] = wtile[ty + (m << 4)][jp];
    const float4 gA = *(const float4*)(Gb + (jp << 7) + c);
    const float4 gB = *(const float4*)(Gb + (jp << 7) + c + 4);
#pragma unroll
    for (int m = 0; m < 4; ++m) ROWFMA(acc[m], wv[m], gA, gB);
  }

  float* __restrict__ dst = part + (size_t)ks * PART_STRIDE + (((size_t)b0) << 7);
#pragma unroll
  for (int m = 0; m < 4; ++m) {
    const int r = ty + (m << 4);
    *(float4*)(dst + ((size_t)r << 7) + c)     = make_float4(acc[m][0], acc[m][1], acc[m][2], acc[m][3]);
    *(float4*)(dst + ((size_t)r << 7) + c + 4) = make_float4(acc[m][4], acc[m][5], acc[m][6], acc[m][7]);
  }
}

// ---------- kernel 4: partial reduce + per-well heads + injector ----------
__global__ __launch_bounds__(256, 2)
void heads_kernel(const float* __restrict__ ut, const float* __restrict__ part,
                  const float* __restrict__ Wh1, const float* __restrict__ bh1,
                  const float* __restrict__ Wh2, const float* __restrict__ bh2,
                  const float* __restrict__ Wh3, const float* __restrict__ bh3,
                  const float* __restrict__ Wi, const float* __restrict__ bi,
                  float* __restrict__ out) {
  __shared__ float zu[8][156];
  __shared__ float g1[8][16][64];
  __shared__ float g2[8][16][64];
  const int t  = threadIdx.x;
  const int b0 = blockIdx.x * 8;
  float* __restrict__ zt1_out = out;
  float* __restrict__ yt1_out = out + (size_t)NB * LAT;

  // phase 0: reduce 8 k-split partials -> zt1, stage zu = [zt1, ut]
  for (int idx = t; idx < 8 * 128; idx += 256) {
    const int r = idx >> 7, i = idx & 127;
    const size_t off = (size_t)(b0 + r) * LAT + i;
    float v = 0.f;
#pragma unroll
    for (int q = 0; q < 8; ++q) v += part[(size_t)q * PART_STRIDE + off];
    zt1_out[off] = v;
    zu[r][i] = v;
  }
  if (t < 8 * UD) {
    const int r = t / UD, u = t - r * UD;
    zu[r][LAT + u] = ut[(size_t)(b0 + r) * UD + u];
  }
  __syncthreads();

  // phase 1: g1 = relu(Wh1 @ zu + bh1). Thread owns (h,o); rows in registers.
#pragma unroll
  for (int q = 0; q < 4; ++q) {
    const int idx = t + (q << 8);            // = h*64 + o
    const float4* __restrict__ wrow = (const float4*)(Wh1 + (size_t)idx * ZUD);
    float accr[8];
    const float bias = bh1[idx];
#pragma unroll
    for (int r = 0; r < 8; ++r) accr[r] = bias;
#pragma unroll 2
    for (int cc = 0; cc < 38; ++cc) {
      const float4 wv = wrow[cc];
#pragma unroll
      for (int r = 0; r < 8; ++r) {
        const float4 zv = *(const float4*)(&zu[r][cc << 2]);
        accr[r] += wv.x * zv.x + wv.y * zv.y + wv.z * zv.z + wv.w * zv.w;
      }
    }
    const int h = idx >> 6, o = idx & 63;
#pragma unroll
    for (int r = 0; r < 8; ++r) g1[r][h][o] = fmaxf(accr[r], 0.f);
  }
  __syncthreads();

  // phase 2: g2 = relu(Wh2 @ g1 + bh2)
#pragma unroll
  for (int q = 0; q < 4; ++q) {
    const int idx = t + (q << 8);            // = h*64 + p
    const int h = idx >> 6, p = idx & 63;
    const float4* __restrict__ wrow = (const float4*)(Wh2 + (size_t)idx * 64);
    float accr[8];
    const float bias = bh2[idx];
#pragma unroll
    for (int r = 0; r < 8; ++r) accr[r] = bias;
#pragma unroll 2
    for (int cc = 0; cc < 16; ++cc) {
      const float4 wv = wrow[cc];
#pragma unroll
      for (int r = 0; r < 8; ++r) {
        const float4 gv = *(const float4*)(&g1[r][h][cc << 2]);
        accr[r] += wv.x * gv.x + wv.y * gv.y + wv.z * gv.z + wv.w * gv.w;
      }
    }
#pragma unroll
    for (int r = 0; r < 8; ++r) g2[r][h][p] = fmaxf(accr[r], 0.f);
  }
  __syncthreads();

  // phase 3: wells (one output per thread: 8 rows x 16 heads x 2)
  {
    const int r = t >> 5, h = (t >> 1) & 15, p = t & 1;
    const float4* __restrict__ wrow = (const float4*)(Wh3 + (size_t)((h << 1) | p) * 64);
    float a0 = 0, a1 = 0, a2 = 0, a3 = 0;
#pragma unroll
    for (int cc = 0; cc < 16; ++cc) {
      const float4 wv = wrow[cc];
      const float4 gv = *(const float4*)(&g2[r][h][cc << 2]);
      a0 = fmaf(wv.x, gv.x, a0); a1 = fmaf(wv.y, gv.y, a1);
      a2 = fmaf(wv.z, gv.z, a2); a3 = fmaf(wv.w, gv.w, a3);
    }
    yt1_out[(size_t)(b0 + r) * 40 + (h << 1) + p] = a0 + a1 + a2 + a3 + bh3[(h << 1) | p];
  }
  // injector
  if (t < 64) {
    const int r = t >> 3, io = t & 7;
    const float4* __restrict__ wrow = (const float4*)(Wi + (size_t)io * ZUD);
    const float4* __restrict__ zr = (const float4*)(&zu[r][0]);
    float a0 = 0, a1 = 0, a2 = 0, a3 = 0;
#pragma unroll
    for (int cc = 0; cc < 38; ++cc) {
      const float4 wv = wrow[cc];
      const float4 zv = zr[cc];
      a0 = fmaf(wv.x, zv.x, a0); a1 = fmaf(wv.y, zv.y, a1);
      a2 = fmaf(wv.z, zv.z, a2); a3 = fmaf(wv.w, zv.w, a3);
    }
    yt1_out[(size_t)(b0 + r) * 40 + 32 + io] = a0 + a1 + a2 + a3 + bi[io];
  }
}

// ---------------------------------------------------------------------------
extern "C" void kernel_launch(void* const* d_in, const int* in_sizes, int n_in,
                              void* d_out, int out_size, void* d_ws, size_t ws_size,
                              hipStream_t stream) {
  const float* zt  = (const float*)d_in[0];
  const float* dt  = (const float*)d_in[1];
  const float* ut  = (const float*)d_in[2];
  const float* We1 = (const float*)d_in[3];
  const float* be1 = (const float*)d_in[4];
  const float* We2 = (const float*)d_in[5];
  const float* be2 = (const float*)d_in[6];
  const float* We3 = (const float*)d_in[7];
  const float* be3 = (const float*)d_in[8];
  const float* WA  = (const float*)d_in[9];
  const float* bA  = (const float*)d_in[10];
  const float* WB  = (const float*)d_in[11];
  const float* bB  = (const float*)d_in[12];
  const float* Wh1 = (const float*)d_in[13];
  const float* bh1 = (const float*)d_in[14];
  const float* Wh2 = (const float*)d_in[15];
  const float* bh2 = (const float*)d_in[16];
  const float* Wh3 = (const float*)d_in[17];
  const float* bh3 = (const float*)d_in[18];
  const float* Wi  = (const float*)d_in[19];
  const float* bi  = (const float*)d_in[20];

  float* ws   = (float*)d_ws;
  float* Gt   = ws + GT_OFF;
  float* Gb   = ws + GB_OFF;
  float* hz   = ws + HZ_OFF;
  float* part = ws + PART_OFF;
  float* out  = (float*)d_out;

  hipLaunchKernelGGL(build_gt_kernel, dim3(152), dim3(256), 0, stream,
                     WA, bA, WB, bB, Gt, Gb);
  hipLaunchKernelGGL(encoder_kernel, dim3(NB / 8), dim3(256), 0, stream,
                     zt, dt, We1, be1, We2, be2, We3, be3, hz);
  hipLaunchKernelGGL(gemm_kernel, dim3(512), dim3(256), 0, stream,
                     zt, dt, ut, Gt, Gb, hz, part);
  hipLaunchKernelGGL(heads_kernel, dim3(NB / 8), dim3(256), 0, stream,
                     ut, part, Wh1, bh1, Wh2, bh2, Wh3, bh3, Wi, bi, out);
}

// Round 3
// 330.447 us; speedup vs baseline: 1.5674x; 1.5674x over previous
//
#include <hip/hip_runtime.h>

// ---------------------------------------------------------------------------
// PerWellMLPTransition on MI355X — round 3: bf16 MFMA for the big contraction.
//
//   zt1[b,i] = sum_{jp,k} w[b,jp]*hz[b,k]*G[jp,k,i] + sum_{jp} w[b,jp]*Gb[jp,i]
//     w[b] = [zt[b,:], ut[b,:]*dt[b]] (152);  G[jp][k][i] from WA/WB.
//
// GEMM: C[4096,128] = P[4096,152*128] * G, P[b,(jp,k)] = w[b,jp]*hz[b,k]
// generated on the fly. P rounded to bf16 (RNE) once; G split hi(trunc)+lo(RNE)
// -> 2 MFMAs (16x16x32_bf16) per tile; est. max abs err ~0.06 < 0.125 tol.
// G pre-arranged in B-fragment order -> fragments loaded straight from L2,
// no LDS staging, no barriers in the jp loop, 4-deep register prefetch.
// ---------------------------------------------------------------------------

#define NB   4096
#define LAT  128
#define UD   24
#define HIDN 200
#define ZUD  152
#define JPD  152

// ws layout (float units)
#define GT_OFF      0u          // frag-ordered G hi/lo bf16: 152*4096 chunks * 16B = 9.96 MB
#define GB_OFF      2490368u    // [152][128] f32
#define HZ_OFF      2509824u    // [4096][128] f32
#define PART_OFF    3034112u    // [4][4096][128] f32
#define PART_STRIDE 524288u

typedef __attribute__((ext_vector_type(8))) short short8_t;
typedef __attribute__((ext_vector_type(4))) float f32x4;

union FragU { short8_t s; unsigned short u[8]; };

__device__ __forceinline__ unsigned short bf16_rne(float x) {
  const unsigned u = __float_as_uint(x);
  return (unsigned short)((u + 0x7FFFu + ((u >> 16) & 1u)) >> 16);
}

// ---------- kernel 1: build fragment-ordered G (hi/lo bf16) + Gb ----------
// chunk c in [0,4096) per jp: c = ((ks*8 + n)*2 + spl)*64 + l
//   lane l supplies B[k = ks*32 + (l>>4)*8 + j][col = n*16 + (l&15)], j=0..7
__global__ __launch_bounds__(256)
void build_gt_kernel(const float* __restrict__ WA, const float* __restrict__ bA,
                     const float* __restrict__ WB, const float* __restrict__ bB,
                     unsigned short* __restrict__ GtU, float* __restrict__ Gb) {
  __shared__ float tile[128][132];   // [i][k]
  const int jp = blockIdx.x;
  const int t  = threadIdx.x;
  const bool isA = (jp < LAT);
  const float* __restrict__ src = isA ? WA : WB;
  const int mul = isA ? LAT : UD;
  const int sub = isA ? jp : (jp - LAT);

  for (int idx = t; idx < 4096; idx += 256) {   // 128 rows x 32 float4 (k-coalesced)
    const int i = idx >> 5, c4 = (idx & 31) << 2;
    *(float4*)(&tile[i][c4]) = *(const float4*)(src + (size_t)(i * mul + sub) * 128 + c4);
  }
  __syncthreads();

  if (t < 128) {
    const float* __restrict__ bsrc = isA ? bA : bB;
    Gb[(jp << 7) + t] = bsrc[t * mul + sub];
  }

  short8_t* __restrict__ G8 = (short8_t*)GtU;
#pragma unroll
  for (int q = 0; q < 16; ++q) {
    const int c   = (q << 8) + t;
    const int l   = c & 63;
    const int spl = (c >> 6) & 1;
    const int n   = (c >> 7) & 7;
    const int ksq = (c >> 10) & 3;
    const int icol = (n << 4) + (l & 15);
    const int k0   = (ksq << 5) + ((l >> 4) << 3);
    FragU fr;
#pragma unroll
    for (int j = 0; j < 8; ++j) {
      const float g = tile[icol][k0 + j];
      if (spl == 0) {
        fr.u[j] = (unsigned short)(__float_as_uint(g) >> 16);          // hi = trunc
      } else {
        const float hif = __uint_as_float(__float_as_uint(g) & 0xFFFF0000u);
        fr.u[j] = bf16_rne(g - hif);                                    // lo = RNE residual
      }
    }
    G8[(size_t)jp * 4096 + c] = fr.s;
  }
}

// ---------- kernel 2: fused 3-layer encoder -> hz (unchanged) ----------
__global__ __launch_bounds__(256, 2)
void encoder_kernel(const float* __restrict__ zt, const float* __restrict__ dt,
                    const float* __restrict__ We1, const float* __restrict__ be1,
                    const float* __restrict__ We2, const float* __restrict__ be2,
                    const float* __restrict__ We3, const float* __restrict__ be3,
                    float* __restrict__ hz) {
  __shared__ float xs[8][132];
  __shared__ float h1[8][200];
  __shared__ float h2[8][200];
  const int t  = threadIdx.x;
  const int b0 = blockIdx.x * 8;

  for (int idx = t; idx < 8 * 129; idx += 256) {
    const int r = idx / 129, c = idx - r * 129;
    xs[r][c] = (c < LAT) ? zt[(size_t)(b0 + r) * LAT + c] : dt[b0 + r];
  }
  __syncthreads();

  if (t < HIDN) {
    const float* __restrict__ w = We1 + t * 129;
    float acc[8];
    const float bias = be1[t];
#pragma unroll
    for (int r = 0; r < 8; ++r) acc[r] = bias;
    for (int c = 0; c < 128; c += 4) {
      const float w0 = w[c], w1 = w[c + 1], w2 = w[c + 2], w3 = w[c + 3];
#pragma unroll
      for (int r = 0; r < 8; ++r) {
        const float4 xv = *(const float4*)(&xs[r][c]);
        acc[r] += xv.x * w0 + xv.y * w1 + xv.z * w2 + xv.w * w3;
      }
    }
    const float wl = w[128];
#pragma unroll
    for (int r = 0; r < 8; ++r) h1[r][t] = fmaxf(fmaf(xs[r][128], wl, acc[r]), 0.f);
  }
  __syncthreads();

  if (t < HIDN) {
    const float* __restrict__ w = We2 + t * HIDN;
    float acc[8];
    const float bias = be2[t];
#pragma unroll
    for (int r = 0; r < 8; ++r) acc[r] = bias;
    for (int c = 0; c < HIDN; c += 4) {
      const float4 wv = *(const float4*)(w + c);
#pragma unroll
      for (int r = 0; r < 8; ++r) {
        const float4 hv = *(const float4*)(&h1[r][c]);
        acc[r] += hv.x * wv.x + hv.y * wv.y + hv.z * wv.z + hv.w * wv.w;
      }
    }
#pragma unroll
    for (int r = 0; r < 8; ++r) h2[r][t] = fmaxf(acc[r], 0.f);
  }
  __syncthreads();

  if (t < LAT) {
    const float* __restrict__ w = We3 + t * HIDN;
    float acc[8];
    const float bias = be3[t];
#pragma unroll
    for (int r = 0; r < 8; ++r) acc[r] = bias;
    for (int c = 0; c < HIDN; c += 4) {
      const float4 wv = *(const float4*)(w + c);
#pragma unroll
      for (int r = 0; r < 8; ++r) {
        const float4 hv = *(const float4*)(&h2[r][c]);
        acc[r] += hv.x * wv.x + hv.y * wv.y + hv.z * wv.z + hv.w * wv.w;
      }
    }
#pragma unroll
    for (int r = 0; r < 8; ++r) hz[(size_t)(b0 + r) * LAT + t] = acc[r];
  }
}

// ---------- kernel 3: MFMA transition GEMM ----------
// grid 256: bid -> x=bid&7, ks=x&3 (XCD-pinned k-slice), mb=(bid>>3)*2+(x>>2).
// 512 thr = 8 waves, wave w: rw=w&1 (rows 32*rw..+32), cw=w>>1 (cols 32*cw..+32);
// wave = 2 mtiles x 2 ntiles of 16x16. No barriers in jp loop; 4-deep prefetch.
#define MFMA_BF16(A, B, C) __builtin_amdgcn_mfma_f32_16x16x32_bf16((A), (B), (C), 0, 0, 0)

#define GBODY(JP, B00, B01, B10, B11, NJP)                                      \
  {                                                                             \
    const int jp_ = (JP);                                                       \
    const float w0_ = wtile[(rw << 5) + lr][jp_];                               \
    const float w1_ = wtile[(rw << 5) + 16 + lr][jp_];                          \
    FragU p0_, p1_;                                                             \
    _Pragma("unroll")                                                           \
    for (int j = 0; j < 8; ++j) {                                               \
      p0_.u[j] = bf16_rne(w0_ * hzr0[j]);                                       \
      p1_.u[j] = bf16_rne(w1_ * hzr1[j]);                                       \
    }                                                                           \
    acc00 = MFMA_BF16(p0_.s, B00, acc00);                                       \
    acc00 = MFMA_BF16(p0_.s, B01, acc00);                                       \
    acc01 = MFMA_BF16(p0_.s, B10, acc01);                                       \
    acc01 = MFMA_BF16(p0_.s, B11, acc01);                                       \
    acc10 = MFMA_BF16(p1_.s, B00, acc10);                                       \
    acc10 = MFMA_BF16(p1_.s, B01, acc10);                                       \
    acc11 = MFMA_BF16(p1_.s, B10, acc11);                                       \
    acc11 = MFMA_BF16(p1_.s, B11, acc11);                                       \
    const size_t nb_ = (size_t)(NJP) * 4096;                                    \
    B00 = G8[nb_ + c00]; B01 = G8[nb_ + c01];                                   \
    B10 = G8[nb_ + c10]; B11 = G8[nb_ + c11];                                   \
  }

__global__ __launch_bounds__(512, 2)
void gemm_mfma_kernel(const float* __restrict__ zt, const float* __restrict__ dt,
                      const float* __restrict__ ut,
                      const unsigned short* __restrict__ GtU,
                      const float* __restrict__ Gb,
                      const float* __restrict__ hz, float* __restrict__ part) {
  __shared__ float wtile[64][156];   // stride 156: 16B-aligned rows, conflict-free reads
  const int t  = threadIdx.x;
  const int l  = t & 63;
  const int w  = t >> 6;
  const int rw = w & 1, cw = w >> 1;
  const int bid = blockIdx.x;
  const int x   = bid & 7;
  const int ks  = x & 3;
  const int mb  = ((bid >> 3) << 1) + (x >> 2);
  const int b0  = mb << 6;
  const int lr  = l & 15, lg = l >> 4;

  // stage w = [zt, ut*dt]
  for (int idx = t; idx < 2048; idx += 512) {
    const int r = idx >> 5, c4 = (idx & 31) << 2;
    *(float4*)(&wtile[r][c4]) = *(const float4*)(zt + (((size_t)(b0 + r)) << 7) + c4);
  }
  for (int idx = t; idx < 384; idx += 512) {
    const int r = idx / 6, u4 = (idx - r * 6) << 2;
    float4 v = *(const float4*)(ut + (size_t)(b0 + r) * UD + u4);
    const float s = dt[b0 + r];
    v.x *= s; v.y *= s; v.z *= s; v.w *= s;
    *(float4*)(&wtile[r][LAT + u4]) = v;
  }
  __syncthreads();

  // hz k-slice -> registers (jp-invariant)
  const int kk = (ks << 5) + (lg << 3);
  float hzr0[8], hzr1[8];
  {
    const float* __restrict__ hp0 = hz + (((size_t)(b0 + (rw << 5) + lr)) << 7) + kk;
    const float* __restrict__ hp1 = hz + (((size_t)(b0 + (rw << 5) + 16 + lr)) << 7) + kk;
    const float4 a0 = *(const float4*)hp0, b0v = *(const float4*)(hp0 + 4);
    const float4 a1 = *(const float4*)hp1, b1v = *(const float4*)(hp1 + 4);
    hzr0[0]=a0.x; hzr0[1]=a0.y; hzr0[2]=a0.z; hzr0[3]=a0.w;
    hzr0[4]=b0v.x; hzr0[5]=b0v.y; hzr0[6]=b0v.z; hzr0[7]=b0v.w;
    hzr1[0]=a1.x; hzr1[1]=a1.y; hzr1[2]=a1.z; hzr1[3]=a1.w;
    hzr1[4]=b1v.x; hzr1[5]=b1v.y; hzr1[6]=b1v.z; hzr1[7]=b1v.w;
  }

  const short8_t* __restrict__ G8 = (const short8_t*)GtU;
  // chunk indices (constant over jp): c = ((ks*8 + n)*2 + spl)*64 + l
  const int n0 = (cw << 1), n1 = (cw << 1) + 1;
  const int c00 = ((((ks << 3) + n0) << 1) + 0) * 64 + l;
  const int c01 = ((((ks << 3) + n0) << 1) + 1) * 64 + l;
  const int c10 = ((((ks << 3) + n1) << 1) + 0) * 64 + l;
  const int c11 = ((((ks << 3) + n1) << 1) + 1) * 64 + l;

  f32x4 acc00 = {0.f,0.f,0.f,0.f}, acc01 = {0.f,0.f,0.f,0.f};
  f32x4 acc10 = {0.f,0.f,0.f,0.f}, acc11 = {0.f,0.f,0.f,0.f};

  // preload 4 phases
  short8_t A0 = G8[(size_t)0*4096 + c00], A1 = G8[(size_t)0*4096 + c01],
           A2 = G8[(size_t)0*4096 + c10], A3 = G8[(size_t)0*4096 + c11];
  short8_t Bv0 = G8[(size_t)1*4096 + c00], Bv1 = G8[(size_t)1*4096 + c01],
           Bv2 = G8[(size_t)1*4096 + c10], Bv3 = G8[(size_t)1*4096 + c11];
  short8_t C0 = G8[(size_t)2*4096 + c00], C1 = G8[(size_t)2*4096 + c01],
           C2 = G8[(size_t)2*4096 + c10], C3 = G8[(size_t)2*4096 + c11];
  short8_t D0 = G8[(size_t)3*4096 + c00], D1 = G8[(size_t)3*4096 + c01],
           D2 = G8[(size_t)3*4096 + c10], D3 = G8[(size_t)3*4096 + c11];

  for (int jp = 0; jp < JPD; jp += 4) {
    const int n4 = (jp + 4 < JPD) ? jp + 4 : JPD - 1;
    const int n5 = (jp + 5 < JPD) ? jp + 5 : JPD - 1;
    const int n6 = (jp + 6 < JPD) ? jp + 6 : JPD - 1;
    const int n7 = (jp + 7 < JPD) ? jp + 7 : JPD - 1;
    GBODY(jp + 0, A0, A1, A2, A3, n4);
    GBODY(jp + 1, Bv0, Bv1, Bv2, Bv3, n5);
    GBODY(jp + 2, C0, C1, C2, C3, n6);
    GBODY(jp + 3, D0, D1, D2, D3, n7);
  }

  // bias contraction in f32, 38 jp per ks (balanced)
  {
    const int j0 = ks * 38;
    for (int jp = j0; jp < j0 + 38; ++jp) {
      const float gb0 = Gb[(jp << 7) + (cw << 5) + lr];
      const float gb1 = Gb[(jp << 7) + (cw << 5) + 16 + lr];
#pragma unroll
      for (int r = 0; r < 4; ++r) {
        const float wv0 = wtile[(rw << 5) + (lg << 2) + r][jp];
        const float wv1 = wtile[(rw << 5) + 16 + (lg << 2) + r][jp];
        acc00[r] += wv0 * gb0; acc01[r] += wv0 * gb1;
        acc10[r] += wv1 * gb0; acc11[r] += wv1 * gb1;
      }
    }
  }

  // store partials: C/D layout col=l&15, row=(l>>4)*4+reg  [m89-verified]
  float* __restrict__ dst = part + (size_t)ks * PART_STRIDE + (((size_t)b0) << 7);
  const int colb = (cw << 5) + lr;
#pragma unroll
  for (int r = 0; r < 4; ++r) {
    const int row0 = (rw << 5) + (lg << 2) + r;
    const int row1 = row0 + 16;
    dst[((size_t)row0 << 7) + colb]      = acc00[r];
    dst[((size_t)row0 << 7) + colb + 16] = acc01[r];
    dst[((size_t)row1 << 7) + colb]      = acc10[r];
    dst[((size_t)row1 << 7) + colb + 16] = acc11[r];
  }
}

// ---------- kernel 4: partial reduce (4 slices) + per-well heads + injector ----------
__global__ __launch_bounds__(256, 2)
void heads_kernel(const float* __restrict__ ut, const float* __restrict__ part,
                  const float* __restrict__ Wh1, const float* __restrict__ bh1,
                  const float* __restrict__ Wh2, const float* __restrict__ bh2,
                  const float* __restrict__ Wh3, const float* __restrict__ bh3,
                  const float* __restrict__ Wi, const float* __restrict__ bi,
                  float* __restrict__ out) {
  __shared__ float zu[8][156];
  __shared__ float g1[8][16][64];
  __shared__ float g2[8][16][64];
  const int t  = threadIdx.x;
  const int b0 = blockIdx.x * 8;
  float* __restrict__ zt1_out = out;
  float* __restrict__ yt1_out = out + (size_t)NB * LAT;

  for (int idx = t; idx < 8 * 128; idx += 256) {
    const int r = idx >> 7, i = idx & 127;
    const size_t off = (size_t)(b0 + r) * LAT + i;
    float v = 0.f;
#pragma unroll
    for (int q = 0; q < 4; ++q) v += part[(size_t)q * PART_STRIDE + off];
    zt1_out[off] = v;
    zu[r][i] = v;
  }
  if (t < 8 * UD) {
    const int r = t / UD, u = t - r * UD;
    zu[r][LAT + u] = ut[(size_t)(b0 + r) * UD + u];
  }
  __syncthreads();

#pragma unroll
  for (int q = 0; q < 4; ++q) {
    const int idx = t + (q << 8);
    const float4* __restrict__ wrow = (const float4*)(Wh1 + (size_t)idx * ZUD);
    float accr[8];
    const float bias = bh1[idx];
#pragma unroll
    for (int r = 0; r < 8; ++r) accr[r] = bias;
#pragma unroll 2
    for (int cc = 0; cc < 38; ++cc) {
      const float4 wv = wrow[cc];
#pragma unroll
      for (int r = 0; r < 8; ++r) {
        const float4 zv = *(const float4*)(&zu[r][cc << 2]);
        accr[r] += wv.x * zv.x + wv.y * zv.y + wv.z * zv.z + wv.w * zv.w;
      }
    }
    const int h = idx >> 6, o = idx & 63;
#pragma unroll
    for (int r = 0; r < 8; ++r) g1[r][h][o] = fmaxf(accr[r], 0.f);
  }
  __syncthreads();

#pragma unroll
  for (int q = 0; q < 4; ++q) {
    const int idx = t + (q << 8);
    const int h = idx >> 6, p = idx & 63;
    const float4* __restrict__ wrow = (const float4*)(Wh2 + (size_t)idx * 64);
    float accr[8];
    const float bias = bh2[idx];
#pragma unroll
    for (int r = 0; r < 8; ++r) accr[r] = bias;
#pragma unroll 2
    for (int cc = 0; cc < 16; ++cc) {
      const float4 wv = wrow[cc];
#pragma unroll
      for (int r = 0; r < 8; ++r) {
        const float4 gv = *(const float4*)(&g1[r][h][cc << 2]);
        accr[r] += wv.x * gv.x + wv.y * gv.y + wv.z * gv.z + wv.w * gv.w;
      }
    }
#pragma unroll
    for (int r = 0; r < 8; ++r) g2[r][h][p] = fmaxf(accr[r], 0.f);
  }
  __syncthreads();

  {
    const int r = t >> 5, h = (t >> 1) & 15, p = t & 1;
    const float4* __restrict__ wrow = (const float4*)(Wh3 + (size_t)((h << 1) | p) * 64);
    float a0 = 0, a1 = 0, a2 = 0, a3 = 0;
#pragma unroll
    for (int cc = 0; cc < 16; ++cc) {
      const float4 wv = wrow[cc];
      const float4 gv = *(const float4*)(&g2[r][h][cc << 2]);
      a0 = fmaf(wv.x, gv.x, a0); a1 = fmaf(wv.y, gv.y, a1);
      a2 = fmaf(wv.z, gv.z, a2); a3 = fmaf(wv.w, gv.w, a3);
    }
    yt1_out[(size_t)(b0 + r) * 40 + (h << 1) + p] = a0 + a1 + a2 + a3 + bh3[(h << 1) | p];
  }
  if (t < 64) {
    const int r = t >> 3, io = t & 7;
    const float4* __restrict__ wrow = (const float4*)(Wi + (size_t)io * ZUD);
    const float4* __restrict__ zr = (const float4*)(&zu[r][0]);
    float a0 = 0, a1 = 0, a2 = 0, a3 = 0;
#pragma unroll
    for (int cc = 0; cc < 38; ++cc) {
      const float4 wv = wrow[cc];
      const float4 zv = zr[cc];
      a0 = fmaf(wv.x, zv.x, a0); a1 = fmaf(wv.y, zv.y, a1);
      a2 = fmaf(wv.z, zv.z, a2); a3 = fmaf(wv.w, zv.w, a3);
    }
    yt1_out[(size_t)(b0 + r) * 40 + 32 + io] = a0 + a1 + a2 + a3 + bi[io];
  }
}

// ---------------------------------------------------------------------------
extern "C" void kernel_launch(void* const* d_in, const int* in_sizes, int n_in,
                              void* d_out, int out_size, void* d_ws, size_t ws_size,
                              hipStream_t stream) {
  const float* zt  = (const float*)d_in[0];
  const float* dt  = (const float*)d_in[1];
  const float* ut  = (const float*)d_in[2];
  const float* We1 = (const float*)d_in[3];
  const float* be1 = (const float*)d_in[4];
  const float* We2 = (const float*)d_in[5];
  const float* be2 = (const float*)d_in[6];
  const float* We3 = (const float*)d_in[7];
  const float* be3 = (const float*)d_in[8];
  const float* WA  = (const float*)d_in[9];
  const float* bA  = (const float*)d_in[10];
  const float* WB  = (const float*)d_in[11];
  const float* bB  = (const float*)d_in[12];
  const float* Wh1 = (const float*)d_in[13];
  const float* bh1 = (const float*)d_in[14];
  const float* Wh2 = (const float*)d_in[15];
  const float* bh2 = (const float*)d_in[16];
  const float* Wh3 = (const float*)d_in[17];
  const float* bh3 = (const float*)d_in[18];
  const float* Wi  = (const float*)d_in[19];
  const float* bi  = (const float*)d_in[20];

  float* ws = (float*)d_ws;
  unsigned short* GtU = (unsigned short*)(ws + GT_OFF);
  float* Gb   = ws + GB_OFF;
  float* hz   = ws + HZ_OFF;
  float* part = ws + PART_OFF;
  float* out  = (float*)d_out;

  hipLaunchKernelGGL(build_gt_kernel, dim3(152), dim3(256), 0, stream,
                     WA, bA, WB, bB, GtU, Gb);
  hipLaunchKernelGGL(encoder_kernel, dim3(NB / 8), dim3(256), 0, stream,
                     zt, dt, We1, be1, We2, be2, We3, be3, hz);
  hipLaunchKernelGGL(gemm_mfma_kernel, dim3(256), dim3(512), 0, stream,
                     zt, dt, ut, GtU, Gb, hz, part);
  hipLaunchKernelGGL(heads_kernel, dim3(NB / 8), dim3(256), 0, stream,
                     ut, part, Wh1, bh1, Wh2, bh2, Wh3, bh3, Wi, bi, out);
}

// Round 4
// 267.458 us; speedup vs baseline: 1.9366x; 1.2355x over previous
//
#include <hip/hip_runtime.h>
#include <hip/hip_bf16.h>

// ---------------------------------------------------------------------------
// PerWellMLPTransition on MI355X — round 4.
//
//   zt1[b,i] = sum_{jp,k} w[b,jp]*hz[b,k]*G[jp,k,i] + sum_{jp} w[b,jp]*Gb[jp,i]
//     w[b] = [zt[b,:], ut[b,:]*dt[b]] (152);  G[jp][k][i] from WA/WB.
//
// GEMM: P[b,(jp,k)] = w[b,jp]*hz[b,k] generated on the fly, rounded to bf16
// via packed cvt (v_cvt_pk_bf16_f32); G split hi(trunc)+lo(RNE) -> 2 MFMAs.
// Round-4: (ks x jph) 8-way split -> 512 blocks = 2/CU (4 waves/SIMD);
// fragment loads straight from L2, no barriers in jp loop, 4-deep prefetch;
// build_gt+encoder fused into one launch.
// ---------------------------------------------------------------------------

#define NB   4096
#define LAT  128
#define UD   24
#define HIDN 200
#define ZUD  152
#define JPD  152

// ws layout (float units)
#define GT_OFF      0u          // frag-ordered G hi/lo bf16: 152*4096 chunks * 16B
#define GB_OFF      2490368u    // [152][128] f32
#define HZ_OFF      2509824u    // [4096][128] f32
#define PART_OFF    3034112u    // [8][4096][128] f32
#define PART_STRIDE 524288u

typedef __attribute__((ext_vector_type(8))) short short8_t;
typedef __attribute__((ext_vector_type(4))) float f32x4;

union FragU { short8_t s; unsigned short u[8]; };
union Frag2 { short8_t s; __hip_bfloat162 h2[4]; };

__device__ __forceinline__ unsigned short bf16_rne(float x) {
  const unsigned u = __float_as_uint(x);
  return (unsigned short)((u + 0x7FFFu + ((u >> 16) & 1u)) >> 16);
}

// ---------- kernel 1: fused {build fragment-ordered G + Gb | encoder} ----------
// blocks [0,152): G packing;  blocks [152, 152+512): encoder (8 rows each).
// chunk c in [0,4096) per jp: c = ((ks*8 + n)*2 + spl)*64 + l
//   lane l supplies B[k = ks*32 + (l>>4)*8 + j][col = n*16 + (l&15)], j=0..7
__global__ __launch_bounds__(256, 2)
void prep_kernel(const float* __restrict__ WA, const float* __restrict__ bA,
                 const float* __restrict__ WB, const float* __restrict__ bB,
                 unsigned short* __restrict__ GtU, float* __restrict__ Gb,
                 const float* __restrict__ zt, const float* __restrict__ dt,
                 const float* __restrict__ We1, const float* __restrict__ be1,
                 const float* __restrict__ We2, const float* __restrict__ be2,
                 const float* __restrict__ We3, const float* __restrict__ be3,
                 float* __restrict__ hz) {
  __shared__ union {
    float tile[128][132];                                        // G-pack path
    struct { float xs[8][132]; float h1[8][200]; float h2[8][200]; } e;  // encoder
  } sh;
  const int t = threadIdx.x;

  if (blockIdx.x < 152) {
    // ---------------- G packing ----------------
    const int jp = blockIdx.x;
    const bool isA = (jp < LAT);
    const float* __restrict__ src = isA ? WA : WB;
    const int mul = isA ? LAT : UD;
    const int sub = isA ? jp : (jp - LAT);

    for (int idx = t; idx < 4096; idx += 256) {   // 128 rows x 32 float4
      const int i = idx >> 5, c4 = (idx & 31) << 2;
      *(float4*)(&sh.tile[i][c4]) = *(const float4*)(src + (size_t)(i * mul + sub) * 128 + c4);
    }
    __syncthreads();

    if (t < 128) {
      const float* __restrict__ bsrc = isA ? bA : bB;
      Gb[(jp << 7) + t] = bsrc[t * mul + sub];
    }

    short8_t* __restrict__ G8 = (short8_t*)GtU;
#pragma unroll
    for (int q = 0; q < 16; ++q) {
      const int c   = (q << 8) + t;
      const int l   = c & 63;
      const int spl = (c >> 6) & 1;
      const int n   = (c >> 7) & 7;
      const int ksq = (c >> 10) & 3;
      const int icol = (n << 4) + (l & 15);
      const int k0   = (ksq << 5) + ((l >> 4) << 3);
      FragU fr;
#pragma unroll
      for (int j = 0; j < 8; ++j) {
        const float g = sh.tile[icol][k0 + j];
        if (spl == 0) {
          fr.u[j] = (unsigned short)(__float_as_uint(g) >> 16);          // hi = trunc
        } else {
          const float hif = __uint_as_float(__float_as_uint(g) & 0xFFFF0000u);
          fr.u[j] = bf16_rne(g - hif);                                    // lo = RNE residual
        }
      }
      G8[(size_t)jp * 4096 + c] = fr.s;
    }
    return;
  }

  // ---------------- encoder ----------------
  const int b0 = (blockIdx.x - 152) * 8;

  for (int idx = t; idx < 8 * 129; idx += 256) {
    const int r = idx / 129, c = idx - r * 129;
    sh.e.xs[r][c] = (c < LAT) ? zt[(size_t)(b0 + r) * LAT + c] : dt[b0 + r];
  }
  __syncthreads();

  if (t < HIDN) {
    const float* __restrict__ w = We1 + t * 129;
    float acc[8];
    const float bias = be1[t];
#pragma unroll
    for (int r = 0; r < 8; ++r) acc[r] = bias;
    for (int c = 0; c < 128; c += 4) {
      const float w0 = w[c], w1 = w[c + 1], w2 = w[c + 2], w3 = w[c + 3];
#pragma unroll
      for (int r = 0; r < 8; ++r) {
        const float4 xv = *(const float4*)(&sh.e.xs[r][c]);
        acc[r] += xv.x * w0 + xv.y * w1 + xv.z * w2 + xv.w * w3;
      }
    }
    const float wl = w[128];
#pragma unroll
    for (int r = 0; r < 8; ++r) sh.e.h1[r][t] = fmaxf(fmaf(sh.e.xs[r][128], wl, acc[r]), 0.f);
  }
  __syncthreads();

  if (t < HIDN) {
    const float* __restrict__ w = We2 + t * HIDN;
    float acc[8];
    const float bias = be2[t];
#pragma unroll
    for (int r = 0; r < 8; ++r) acc[r] = bias;
    for (int c = 0; c < HIDN; c += 4) {
      const float4 wv = *(const float4*)(w + c);
#pragma unroll
      for (int r = 0; r < 8; ++r) {
        const float4 hv = *(const float4*)(&sh.e.h1[r][c]);
        acc[r] += hv.x * wv.x + hv.y * wv.y + hv.z * wv.z + hv.w * wv.w;
      }
    }
#pragma unroll
    for (int r = 0; r < 8; ++r) sh.e.h2[r][t] = fmaxf(acc[r], 0.f);
  }
  __syncthreads();

  if (t < LAT) {
    const float* __restrict__ w = We3 + t * HIDN;
    float acc[8];
    const float bias = be3[t];
#pragma unroll
    for (int r = 0; r < 8; ++r) acc[r] = bias;
    for (int c = 0; c < HIDN; c += 4) {
      const float4 wv = *(const float4*)(w + c);
#pragma unroll
      for (int r = 0; r < 8; ++r) {
        const float4 hv = *(const float4*)(&sh.e.h2[r][c]);
        acc[r] += hv.x * wv.x + hv.y * wv.y + hv.z * wv.z + hv.w * wv.w;
      }
    }
#pragma unroll
    for (int r = 0; r < 8; ++r) hz[(size_t)(b0 + r) * LAT + t] = acc[r];
  }
}

// ---------- kernel 2: MFMA transition GEMM ----------
// grid 512: combo = bid&7 (XCD-pinned) -> ks = combo&3 (k-slice of 32),
// jph = combo>>2 (jp half of 76); mb = bid>>3 -> rows b0 = mb*64.
// 512 thr = 8 waves (2 rw x 4 cw); wave = 2 mtiles x 2 ntiles of 16x16.
// No barriers in jp loop; 4-deep register prefetch of B fragments.
#define MFMA_BF16(A, B, C) __builtin_amdgcn_mfma_f32_16x16x32_bf16((A), (B), (C), 0, 0, 0)

#define GBODY(JP, B00, B01, B10, B11, NJP)                                      \
  {                                                                             \
    const int jp_ = (JP);                                                       \
    const float w0_ = wtile[(rw << 5) + lr][jp_];                               \
    const float w1_ = wtile[(rw << 5) + 16 + lr][jp_];                          \
    Frag2 p0_, p1_;                                                             \
    _Pragma("unroll")                                                           \
    for (int jq = 0; jq < 4; ++jq) {                                            \
      p0_.h2[jq] = __float22bfloat162_rn(                                       \
          make_float2(w0_ * hzr0[2 * jq], w0_ * hzr0[2 * jq + 1]));             \
      p1_.h2[jq] = __float22bfloat162_rn(                                       \
          make_float2(w1_ * hzr1[2 * jq], w1_ * hzr1[2 * jq + 1]));             \
    }                                                                           \
    acc00 = MFMA_BF16(p0_.s, B00, acc00);                                       \
    acc00 = MFMA_BF16(p0_.s, B01, acc00);                                       \
    acc01 = MFMA_BF16(p0_.s, B10, acc01);                                       \
    acc01 = MFMA_BF16(p0_.s, B11, acc01);                                       \
    acc10 = MFMA_BF16(p1_.s, B00, acc10);                                       \
    acc10 = MFMA_BF16(p1_.s, B01, acc10);                                       \
    acc11 = MFMA_BF16(p1_.s, B10, acc11);                                       \
    acc11 = MFMA_BF16(p1_.s, B11, acc11);                                       \
    const size_t nb_ = (size_t)(NJP) * 4096;                                    \
    B00 = G8[nb_ + c00]; B01 = G8[nb_ + c01];                                   \
    B10 = G8[nb_ + c10]; B11 = G8[nb_ + c11];                                   \
  }

__global__ __launch_bounds__(512, 4)
void gemm_mfma_kernel(const float* __restrict__ zt, const float* __restrict__ dt,
                      const float* __restrict__ ut,
                      const unsigned short* __restrict__ GtU,
                      const float* __restrict__ Gb,
                      const float* __restrict__ hz, float* __restrict__ part) {
  __shared__ float wtile[64][156];   // stride 156: 16B-aligned rows, conflict-free reads
  const int t  = threadIdx.x;
  const int l  = t & 63;
  const int w  = t >> 6;
  const int rw = w & 1, cw = w >> 1;
  const int bid   = blockIdx.x;
  const int combo = bid & 7;         // XCD-pinned (ks, jph) pair
  const int ks    = combo & 3;
  const int jph   = combo >> 2;
  const int b0    = (bid >> 3) << 6;
  const int lr  = l & 15, lg = l >> 4;
  const int j0  = jph * 76;

  // stage w = [zt, ut*dt]
  for (int idx = t; idx < 2048; idx += 512) {
    const int r = idx >> 5, c4 = (idx & 31) << 2;
    *(float4*)(&wtile[r][c4]) = *(const float4*)(zt + (((size_t)(b0 + r)) << 7) + c4);
  }
  for (int idx = t; idx < 384; idx += 512) {
    const int r = idx / 6, u4 = (idx - r * 6) << 2;
    float4 v = *(const float4*)(ut + (size_t)(b0 + r) * UD + u4);
    const float s = dt[b0 + r];
    v.x *= s; v.y *= s; v.z *= s; v.w *= s;
    *(float4*)(&wtile[r][LAT + u4]) = v;
  }
  __syncthreads();

  // hz k-slice -> registers (jp-invariant)
  const int kk = (ks << 5) + (lg << 3);
  float hzr0[8], hzr1[8];
  {
    const float* __restrict__ hp0 = hz + (((size_t)(b0 + (rw << 5) + lr)) << 7) + kk;
    const float* __restrict__ hp1 = hz + (((size_t)(b0 + (rw << 5) + 16 + lr)) << 7) + kk;
    const float4 a0 = *(const float4*)hp0, b0v = *(const float4*)(hp0 + 4);
    const float4 a1 = *(const float4*)hp1, b1v = *(const float4*)(hp1 + 4);
    hzr0[0]=a0.x; hzr0[1]=a0.y; hzr0[2]=a0.z; hzr0[3]=a0.w;
    hzr0[4]=b0v.x; hzr0[5]=b0v.y; hzr0[6]=b0v.z; hzr0[7]=b0v.w;
    hzr1[0]=a1.x; hzr1[1]=a1.y; hzr1[2]=a1.z; hzr1[3]=a1.w;
    hzr1[4]=b1v.x; hzr1[5]=b1v.y; hzr1[6]=b1v.z; hzr1[7]=b1v.w;
  }

  const short8_t* __restrict__ G8 = (const short8_t*)GtU;
  // chunk indices (constant over jp): c = ((ks*8 + n)*2 + spl)*64 + l
  const int n0 = (cw << 1), n1 = (cw << 1) + 1;
  const int c00 = ((((ks << 3) + n0) << 1) + 0) * 64 + l;
  const int c01 = ((((ks << 3) + n0) << 1) + 1) * 64 + l;
  const int c10 = ((((ks << 3) + n1) << 1) + 0) * 64 + l;
  const int c11 = ((((ks << 3) + n1) << 1) + 1) * 64 + l;

  f32x4 acc00 = {0.f,0.f,0.f,0.f}, acc01 = {0.f,0.f,0.f,0.f};
  f32x4 acc10 = {0.f,0.f,0.f,0.f}, acc11 = {0.f,0.f,0.f,0.f};

  // preload 4 jp phases
  short8_t A0 = G8[(size_t)(j0+0)*4096 + c00], A1 = G8[(size_t)(j0+0)*4096 + c01],
           A2 = G8[(size_t)(j0+0)*4096 + c10], A3 = G8[(size_t)(j0+0)*4096 + c11];
  short8_t Bv0 = G8[(size_t)(j0+1)*4096 + c00], Bv1 = G8[(size_t)(j0+1)*4096 + c01],
           Bv2 = G8[(size_t)(j0+1)*4096 + c10], Bv3 = G8[(size_t)(j0+1)*4096 + c11];
  short8_t C0 = G8[(size_t)(j0+2)*4096 + c00], C1 = G8[(size_t)(j0+2)*4096 + c01],
           C2 = G8[(size_t)(j0+2)*4096 + c10], C3 = G8[(size_t)(j0+2)*4096 + c11];
  short8_t D0 = G8[(size_t)(j0+3)*4096 + c00], D1 = G8[(size_t)(j0+3)*4096 + c01],
           D2 = G8[(size_t)(j0+3)*4096 + c10], D3 = G8[(size_t)(j0+3)*4096 + c11];

  const int jend = j0 + 76;
  for (int jp = j0; jp < jend; jp += 4) {
    const int n4 = (jp + 4 < jend) ? jp + 4 : jend - 1;
    const int n5 = (jp + 5 < jend) ? jp + 5 : jend - 1;
    const int n6 = (jp + 6 < jend) ? jp + 6 : jend - 1;
    const int n7 = (jp + 7 < jend) ? jp + 7 : jend - 1;
    GBODY(jp + 0, A0, A1, A2, A3, n4);
    GBODY(jp + 1, Bv0, Bv1, Bv2, Bv3, n5);
    GBODY(jp + 2, C0, C1, C2, C3, n6);
    GBODY(jp + 3, D0, D1, D2, D3, n7);
  }

  // bias contraction in f32, 19 jp per combo (balanced across all 8 splits)
  {
    const int jb0 = combo * 19;
    for (int jp = jb0; jp < jb0 + 19; ++jp) {
      const float gb0 = Gb[(jp << 7) + (cw << 5) + lr];
      const float gb1 = Gb[(jp << 7) + (cw << 5) + 16 + lr];
#pragma unroll
      for (int r = 0; r < 4; ++r) {
        const float wv0 = wtile[(rw << 5) + (lg << 2) + r][jp];
        const float wv1 = wtile[(rw << 5) + 16 + (lg << 2) + r][jp];
        acc00[r] += wv0 * gb0; acc01[r] += wv0 * gb1;
        acc10[r] += wv1 * gb0; acc11[r] += wv1 * gb1;
      }
    }
  }

  // store partials: C/D layout col=l&15, row=(l>>4)*4+reg  [m89-verified]
  float* __restrict__ dst = part + (size_t)combo * PART_STRIDE + (((size_t)b0) << 7);
  const int colb = (cw << 5) + lr;
#pragma unroll
  for (int r = 0; r < 4; ++r) {
    const int row0 = (rw << 5) + (lg << 2) + r;
    const int row1 = row0 + 16;
    dst[((size_t)row0 << 7) + colb]      = acc00[r];
    dst[((size_t)row0 << 7) + colb + 16] = acc01[r];
    dst[((size_t)row1 << 7) + colb]      = acc10[r];
    dst[((size_t)row1 << 7) + colb + 16] = acc11[r];
  }
}

// ---------- kernel 3: partial reduce (8 slices) + per-well heads + injector ----------
__global__ __launch_bounds__(256, 2)
void heads_kernel(const float* __restrict__ ut, const float* __restrict__ part,
                  const float* __restrict__ Wh1, const float* __restrict__ bh1,
                  const float* __restrict__ Wh2, const float* __restrict__ bh2,
                  const float* __restrict__ Wh3, const float* __restrict__ bh3,
                  const float* __restrict__ Wi, const float* __restrict__ bi,
                  float* __restrict__ out) {
  __shared__ float zu[8][156];
  __shared__ float g1[8][16][64];
  __shared__ float g2[8][16][64];
  const int t  = threadIdx.x;
  const int b0 = blockIdx.x * 8;
  float* __restrict__ zt1_out = out;
  float* __restrict__ yt1_out = out + (size_t)NB * LAT;

  for (int idx = t; idx < 8 * 128; idx += 256) {
    const int r = idx >> 7, i = idx & 127;
    const size_t off = (size_t)(b0 + r) * LAT + i;
    float v = 0.f;
#pragma unroll
    for (int q = 0; q < 8; ++q) v += part[(size_t)q * PART_STRIDE + off];
    zt1_out[off] = v;
    zu[r][i] = v;
  }
  if (t < 8 * UD) {
    const int r = t / UD, u = t - r * UD;
    zu[r][LAT + u] = ut[(size_t)(b0 + r) * UD + u];
  }
  __syncthreads();

#pragma unroll
  for (int q = 0; q < 4; ++q) {
    const int idx = t + (q << 8);
    const float4* __restrict__ wrow = (const float4*)(Wh1 + (size_t)idx * ZUD);
    float accr[8];
    const float bias = bh1[idx];
#pragma unroll
    for (int r = 0; r < 8; ++r) accr[r] = bias;
#pragma unroll 2
    for (int cc = 0; cc < 38; ++cc) {
      const float4 wv = wrow[cc];
#pragma unroll
      for (int r = 0; r < 8; ++r) {
        const float4 zv = *(const float4*)(&zu[r][cc << 2]);
        accr[r] += wv.x * zv.x + wv.y * zv.y + wv.z * zv.z + wv.w * zv.w;
      }
    }
    const int h = idx >> 6, o = idx & 63;
#pragma unroll
    for (int r = 0; r < 8; ++r) g1[r][h][o] = fmaxf(accr[r], 0.f);
  }
  __syncthreads();

#pragma unroll
  for (int q = 0; q < 4; ++q) {
    const int idx = t + (q << 8);
    const int h = idx >> 6, p = idx & 63;
    const float4* __restrict__ wrow = (const float4*)(Wh2 + (size_t)idx * 64);
    float accr[8];
    const float bias = bh2[idx];
#pragma unroll
    for (int r = 0; r < 8; ++r) accr[r] = bias;
#pragma unroll 2
    for (int cc = 0; cc < 16; ++cc) {
      const float4 wv = wrow[cc];
#pragma unroll
      for (int r = 0; r < 8; ++r) {
        const float4 gv = *(const float4*)(&g1[r][h][cc << 2]);
        accr[r] += wv.x * gv.x + wv.y * gv.y + wv.z * gv.z + wv.w * gv.w;
      }
    }
#pragma unroll
    for (int r = 0; r < 8; ++r) g2[r][h][p] = fmaxf(accr[r], 0.f);
  }
  __syncthreads();

  {
    const int r = t >> 5, h = (t >> 1) & 15, p = t & 1;
    const float4* __restrict__ wrow = (const float4*)(Wh3 + (size_t)((h << 1) | p) * 64);
    float a0 = 0, a1 = 0, a2 = 0, a3 = 0;
#pragma unroll
    for (int cc = 0; cc < 16; ++cc) {
      const float4 wv = wrow[cc];
      const float4 gv = *(const float4*)(&g2[r][h][cc << 2]);
      a0 = fmaf(wv.x, gv.x, a0); a1 = fmaf(wv.y, gv.y, a1);
      a2 = fmaf(wv.z, gv.z, a2); a3 = fmaf(wv.w, gv.w, a3);
    }
    yt1_out[(size_t)(b0 + r) * 40 + (h << 1) + p] = a0 + a1 + a2 + a3 + bh3[(h << 1) | p];
  }
  if (t < 64) {
    const int r = t >> 3, io = t & 7;
    const float4* __restrict__ wrow = (const float4*)(Wi + (size_t)io * ZUD);
    const float4* __restrict__ zr = (const float4*)(&zu[r][0]);
    float a0 = 0, a1 = 0, a2 = 0, a3 = 0;
#pragma unroll
    for (int cc = 0; cc < 38; ++cc) {
      const float4 wv = wrow[cc];
      const float4 zv = zr[cc];
      a0 = fmaf(wv.x, zv.x, a0); a1 = fmaf(wv.y, zv.y, a1);
      a2 = fmaf(wv.z, zv.z, a2); a3 = fmaf(wv.w, zv.w, a3);
    }
    yt1_out[(size_t)(b0 + r) * 40 + 32 + io] = a0 + a1 + a2 + a3 + bi[io];
  }
}

// ---------------------------------------------------------------------------
extern "C" void kernel_launch(void* const* d_in, const int* in_sizes, int n_in,
                              void* d_out, int out_size, void* d_ws, size_t ws_size,
                              hipStream_t stream) {
  const float* zt  = (const float*)d_in[0];
  const float* dt  = (const float*)d_in[1];
  const float* ut  = (const float*)d_in[2];
  const float* We1 = (const float*)d_in[3];
  const float* be1 = (const float*)d_in[4];
  const float* We2 = (const float*)d_in[5];
  const float* be2 = (const float*)d_in[6];
  const float* We3 = (const float*)d_in[7];
  const float* be3 = (const float*)d_in[8];
  const float* WA  = (const float*)d_in[9];
  const float* bA  = (const float*)d_in[10];
  const float* WB  = (const float*)d_in[11];
  const float* bB  = (const float*)d_in[12];
  const float* Wh1 = (const float*)d_in[13];
  const float* bh1 = (const float*)d_in[14];
  const float* Wh2 = (const float*)d_in[15];
  const float* bh2 = (const float*)d_in[16];
  const float* Wh3 = (const float*)d_in[17];
  const float* bh3 = (const float*)d_in[18];
  const float* Wi  = (const float*)d_in[19];
  const float* bi  = (const float*)d_in[20];

  float* ws = (float*)d_ws;
  unsigned short* GtU = (unsigned short*)(ws + GT_OFF);
  float* Gb   = ws + GB_OFF;
  float* hz   = ws + HZ_OFF;
  float* part = ws + PART_OFF;
  float* out  = (float*)d_out;

  hipLaunchKernelGGL(prep_kernel, dim3(152 + NB / 8), dim3(256), 0, stream,
                     WA, bA, WB, bB, GtU, Gb,
                     zt, dt, We1, be1, We2, be2, We3, be3, hz);
  hipLaunchKernelGGL(gemm_mfma_kernel, dim3(512), dim3(512), 0, stream,
                     zt, dt, ut, GtU, Gb, hz, part);
  hipLaunchKernelGGL(heads_kernel, dim3(NB / 8), dim3(256), 0, stream,
                     ut, part, Wh1, bh1, Wh2, bh2, Wh3, bh3, Wi, bi, out);
}

// Round 5
// 231.919 us; speedup vs baseline: 2.2334x; 1.1532x over previous
//
#include <hip/hip_runtime.h>
#include <hip/hip_bf16.h>

// ---------------------------------------------------------------------------
// PerWellMLPTransition on MI355X — round 5: MFMA heads.
//
//   zt1[b,i] = sum_{jp,k} w[b,jp]*hz[b,k]*G[jp,k,i] + sum_{jp} w[b,jp]*Gb[jp,i]
//   heads: 3-layer per-well MLPs + injector, now on matrix cores with
//   hi/lo-split bf16 operands (3-product MFMA, err ~1e-4).
// ---------------------------------------------------------------------------

#define NB   4096
#define LAT  128
#define UD   24
#define HIDN 200
#define ZUD  152
#define JPD  152

// ws layout (float units)
#define GT_OFF      0u          // frag-ordered G hi/lo bf16 (152*4096 chunks * 16B)
#define GB_OFF      2490368u    // [152][128] f32
#define HZ_OFF      2509824u    // [4096][128] f32
#define PART_OFF    3034112u    // [8][4096][128] f32
#define PART_STRIDE 524288u
#define WH1P_OFF    7228416u    // 16*2560 chunks * 16B = 655360 B
#define WH2P_OFF    7392256u    // 16*1024 chunks * 16B
#define WH3P_OFF    7457792u    // 16*256 chunks * 16B   (end: 7474176 floats)

typedef __attribute__((ext_vector_type(8))) short short8_t;
typedef __attribute__((ext_vector_type(4))) float f32x4;

union FragU { short8_t s; unsigned short u[8]; };
union Frag2 { short8_t s; __hip_bfloat162 h2[4]; };

__device__ __forceinline__ unsigned short bf16_rne(float x) {
  const unsigned u = __float_as_uint(x);
  return (unsigned short)((u + 0x7FFFu + ((u >> 16) & 1u)) >> 16);
}
__device__ __forceinline__ unsigned short bf16_hi(float x) {
  return (unsigned short)(__float_as_uint(x) >> 16);
}
__device__ __forceinline__ unsigned short bf16_lo(float x) {
  const float hif = __uint_as_float(__float_as_uint(x) & 0xFFFF0000u);
  return bf16_rne(x - hif);
}

#define MFMA_BF16(A, B, C) __builtin_amdgcn_mfma_f32_16x16x32_bf16((A), (B), (C), 0, 0, 0)

// ---------- kernel 1: prep = {G pack | encoder | head-weight pack} ----------
// blocks [0,152): G;  [152,664): encoder;  [664,680): head h weight pack.
__global__ __launch_bounds__(256, 2)
void prep_kernel(const float* __restrict__ WA, const float* __restrict__ bA,
                 const float* __restrict__ WB, const float* __restrict__ bB,
                 unsigned short* __restrict__ GtU, float* __restrict__ Gb,
                 const float* __restrict__ zt, const float* __restrict__ dt,
                 const float* __restrict__ We1, const float* __restrict__ be1,
                 const float* __restrict__ We2, const float* __restrict__ be2,
                 const float* __restrict__ We3, const float* __restrict__ be3,
                 float* __restrict__ hz,
                 const float* __restrict__ Wh1, const float* __restrict__ Wh2,
                 const float* __restrict__ Wh3,
                 short8_t* __restrict__ WH1P, short8_t* __restrict__ WH2P,
                 short8_t* __restrict__ WH3P) {
  __shared__ union {
    float tile[128][132];
    struct { float xs[8][132]; float h1[8][200]; float h2[8][200]; } e;
    struct { float w1[64][152]; float w2[64][64]; float w3[2][64]; } hp;
  } sh;
  const int t = threadIdx.x;

  if (blockIdx.x < 152) {
    // ---------------- G packing ----------------
    const int jp = blockIdx.x;
    const bool isA = (jp < LAT);
    const float* __restrict__ src = isA ? WA : WB;
    const int mul = isA ? LAT : UD;
    const int sub = isA ? jp : (jp - LAT);

    for (int idx = t; idx < 4096; idx += 256) {
      const int i = idx >> 5, c4 = (idx & 31) << 2;
      *(float4*)(&sh.tile[i][c4]) = *(const float4*)(src + (size_t)(i * mul + sub) * 128 + c4);
    }
    __syncthreads();

    if (t < 128) {
      const float* __restrict__ bsrc = isA ? bA : bB;
      Gb[(jp << 7) + t] = bsrc[t * mul + sub];
    }

    short8_t* __restrict__ G8 = (short8_t*)GtU;
#pragma unroll
    for (int q = 0; q < 16; ++q) {
      const int c   = (q << 8) + t;
      const int l   = c & 63;
      const int spl = (c >> 6) & 1;
      const int n   = (c >> 7) & 7;
      const int ksq = (c >> 10) & 3;
      const int icol = (n << 4) + (l & 15);
      const int k0   = (ksq << 5) + ((l >> 4) << 3);
      FragU fr;
#pragma unroll
      for (int j = 0; j < 8; ++j) {
        const float g = sh.tile[icol][k0 + j];
        fr.u[j] = spl ? bf16_lo(g) : bf16_hi(g);
      }
      G8[(size_t)jp * 4096 + c] = fr.s;
    }
    return;
  }

  if (blockIdx.x >= 664) {
    // ---------------- head-weight packing (head h) ----------------
    const int h = blockIdx.x - 664;
    for (int idx = t; idx < 2432; idx += 256) {        // Wh1[h]: 64x152
      const int r = idx / 38, c4 = (idx - r * 38) << 2;
      *(float4*)(&sh.hp.w1[r][c4]) = *(const float4*)(Wh1 + ((size_t)h * 64 + r) * ZUD + c4);
    }
    for (int idx = t; idx < 1024; idx += 256) {        // Wh2[h]: 64x64
      const int r = idx >> 4, c4 = (idx & 15) << 2;
      *(float4*)(&sh.hp.w2[r][c4]) = *(const float4*)(Wh2 + ((size_t)h * 64 + r) * 64 + c4);
    }
    if (t < 32) {                                      // Wh3[h]: 2x64
      const int r = t >> 4, c4 = (t & 15) << 2;
      *(float4*)(&sh.hp.w3[r][c4]) = *(const float4*)(Wh3 + ((size_t)h * 2 + r) * 64 + c4);
    }
    __syncthreads();

    // WH1P: chunk c = ((ks*4+nt)*2+spl)*64+l, K padded 152->160
    for (int c = t; c < 2560; c += 256) {
      const int l = c & 63, spl = (c >> 6) & 1, nt = (c >> 7) & 3, ks = c >> 9;
      const int col = (nt << 4) + (l & 15);
      const int k0  = (ks << 5) + ((l >> 4) << 3);
      FragU fr;
#pragma unroll
      for (int j = 0; j < 8; ++j) {
        const int k = k0 + j;
        const float v = (k < ZUD) ? sh.hp.w1[col][k] : 0.f;
        fr.u[j] = spl ? bf16_lo(v) : bf16_hi(v);
      }
      WH1P[(size_t)h * 2560 + c] = fr.s;
    }
    // WH2P: K=64
    for (int c = t; c < 1024; c += 256) {
      const int l = c & 63, spl = (c >> 6) & 1, nt = (c >> 7) & 3, ks = (c >> 9) & 1;
      const int col = (nt << 4) + (l & 15);
      const int k0  = (ks << 5) + ((l >> 4) << 3);
      FragU fr;
#pragma unroll
      for (int j = 0; j < 8; ++j) {
        const float v = sh.hp.w2[col][k0 + j];
        fr.u[j] = spl ? bf16_lo(v) : bf16_hi(v);
      }
      WH2P[(size_t)h * 1024 + c] = fr.s;
    }
    // WH3P: K=64, N=16 (cols>=2 zero)
    for (int c = t; c < 256; c += 256) {
      const int l = c & 63, spl = (c >> 6) & 1, ks = (c >> 7) & 1;
      const int col = l & 15;
      const int k0  = (ks << 5) + ((l >> 4) << 3);
      FragU fr;
#pragma unroll
      for (int j = 0; j < 8; ++j) {
        const float v = (col < 2) ? sh.hp.w3[col][k0 + j] : 0.f;
        fr.u[j] = spl ? bf16_lo(v) : bf16_hi(v);
      }
      WH3P[(size_t)h * 256 + c] = fr.s;
    }
    return;
  }

  // ---------------- encoder ----------------
  const int b0 = (blockIdx.x - 152) * 8;

  for (int idx = t; idx < 8 * 129; idx += 256) {
    const int r = idx / 129, c = idx - r * 129;
    sh.e.xs[r][c] = (c < LAT) ? zt[(size_t)(b0 + r) * LAT + c] : dt[b0 + r];
  }
  __syncthreads();

  if (t < HIDN) {
    const float* __restrict__ w = We1 + t * 129;
    float acc[8];
    const float bias = be1[t];
#pragma unroll
    for (int r = 0; r < 8; ++r) acc[r] = bias;
    for (int c = 0; c < 128; c += 4) {
      const float w0 = w[c], w1 = w[c + 1], w2 = w[c + 2], w3 = w[c + 3];
#pragma unroll
      for (int r = 0; r < 8; ++r) {
        const float4 xv = *(const float4*)(&sh.e.xs[r][c]);
        acc[r] += xv.x * w0 + xv.y * w1 + xv.z * w2 + xv.w * w3;
      }
    }
    const float wl = w[128];
#pragma unroll
    for (int r = 0; r < 8; ++r) sh.e.h1[r][t] = fmaxf(fmaf(sh.e.xs[r][128], wl, acc[r]), 0.f);
  }
  __syncthreads();

  if (t < HIDN) {
    const float* __restrict__ w = We2 + t * HIDN;
    float acc[8];
    const float bias = be2[t];
#pragma unroll
    for (int r = 0; r < 8; ++r) acc[r] = bias;
    for (int c = 0; c < HIDN; c += 4) {
      const float4 wv = *(const float4*)(w + c);
#pragma unroll
      for (int r = 0; r < 8; ++r) {
        const float4 hv = *(const float4*)(&sh.e.h1[r][c]);
        acc[r] += hv.x * wv.x + hv.y * wv.y + hv.z * wv.z + hv.w * wv.w;
      }
    }
#pragma unroll
    for (int r = 0; r < 8; ++r) sh.e.h2[r][t] = fmaxf(acc[r], 0.f);
  }
  __syncthreads();

  if (t < LAT) {
    const float* __restrict__ w = We3 + t * HIDN;
    float acc[8];
    const float bias = be3[t];
#pragma unroll
    for (int r = 0; r < 8; ++r) acc[r] = bias;
    for (int c = 0; c < HIDN; c += 4) {
      const float4 wv = *(const float4*)(w + c);
#pragma unroll
      for (int r = 0; r < 8; ++r) {
        const float4 hv = *(const float4*)(&sh.e.h2[r][c]);
        acc[r] += hv.x * wv.x + hv.y * wv.y + hv.z * wv.z + hv.w * wv.w;
      }
    }
#pragma unroll
    for (int r = 0; r < 8; ++r) hz[(size_t)(b0 + r) * LAT + t] = acc[r];
  }
}

// ---------- kernel 2: MFMA transition GEMM (unchanged from round 4) ----------
#define GBODY(JP, B00, B01, B10, B11, NJP)                                      \
  {                                                                             \
    const int jp_ = (JP);                                                       \
    const float w0_ = wtile[(rw << 5) + lr][jp_];                               \
    const float w1_ = wtile[(rw << 5) + 16 + lr][jp_];                          \
    Frag2 p0_, p1_;                                                             \
    _Pragma("unroll")                                                           \
    for (int jq = 0; jq < 4; ++jq) {                                            \
      p0_.h2[jq] = __float22bfloat162_rn(                                       \
          make_float2(w0_ * hzr0[2 * jq], w0_ * hzr0[2 * jq + 1]));             \
      p1_.h2[jq] = __float22bfloat162_rn(                                       \
          make_float2(w1_ * hzr1[2 * jq], w1_ * hzr1[2 * jq + 1]));             \
    }                                                                           \
    acc00 = MFMA_BF16(p0_.s, B00, acc00);                                       \
    acc00 = MFMA_BF16(p0_.s, B01, acc00);                                       \
    acc01 = MFMA_BF16(p0_.s, B10, acc01);                                       \
    acc01 = MFMA_BF16(p0_.s, B11, acc01);                                       \
    acc10 = MFMA_BF16(p1_.s, B00, acc10);                                       \
    acc10 = MFMA_BF16(p1_.s, B01, acc10);                                       \
    acc11 = MFMA_BF16(p1_.s, B10, acc11);                                       \
    acc11 = MFMA_BF16(p1_.s, B11, acc11);                                       \
    const size_t nb_ = (size_t)(NJP) * 4096;                                    \
    B00 = G8[nb_ + c00]; B01 = G8[nb_ + c01];                                   \
    B10 = G8[nb_ + c10]; B11 = G8[nb_ + c11];                                   \
  }

__global__ __launch_bounds__(512, 4)
void gemm_mfma_kernel(const float* __restrict__ zt, const float* __restrict__ dt,
                      const float* __restrict__ ut,
                      const unsigned short* __restrict__ GtU,
                      const float* __restrict__ Gb,
                      const float* __restrict__ hz, float* __restrict__ part) {
  __shared__ float wtile[64][156];
  const int t  = threadIdx.x;
  const int l  = t & 63;
  const int w  = t >> 6;
  const int rw = w & 1, cw = w >> 1;
  const int bid   = blockIdx.x;
  const int combo = bid & 7;
  const int ks    = combo & 3;
  const int jph   = combo >> 2;
  const int b0    = (bid >> 3) << 6;
  const int lr  = l & 15, lg = l >> 4;
  const int j0  = jph * 76;

  for (int idx = t; idx < 2048; idx += 512) {
    const int r = idx >> 5, c4 = (idx & 31) << 2;
    *(float4*)(&wtile[r][c4]) = *(const float4*)(zt + (((size_t)(b0 + r)) << 7) + c4);
  }
  for (int idx = t; idx < 384; idx += 512) {
    const int r = idx / 6, u4 = (idx - r * 6) << 2;
    float4 v = *(const float4*)(ut + (size_t)(b0 + r) * UD + u4);
    const float s = dt[b0 + r];
    v.x *= s; v.y *= s; v.z *= s; v.w *= s;
    *(float4*)(&wtile[r][LAT + u4]) = v;
  }
  __syncthreads();

  const int kk = (ks << 5) + (lg << 3);
  float hzr0[8], hzr1[8];
  {
    const float* __restrict__ hp0 = hz + (((size_t)(b0 + (rw << 5) + lr)) << 7) + kk;
    const float* __restrict__ hp1 = hz + (((size_t)(b0 + (rw << 5) + 16 + lr)) << 7) + kk;
    const float4 a0 = *(const float4*)hp0, b0v = *(const float4*)(hp0 + 4);
    const float4 a1 = *(const float4*)hp1, b1v = *(const float4*)(hp1 + 4);
    hzr0[0]=a0.x; hzr0[1]=a0.y; hzr0[2]=a0.z; hzr0[3]=a0.w;
    hzr0[4]=b0v.x; hzr0[5]=b0v.y; hzr0[6]=b0v.z; hzr0[7]=b0v.w;
    hzr1[0]=a1.x; hzr1[1]=a1.y; hzr1[2]=a1.z; hzr1[3]=a1.w;
    hzr1[4]=b1v.x; hzr1[5]=b1v.y; hzr1[6]=b1v.z; hzr1[7]=b1v.w;
  }

  const short8_t* __restrict__ G8 = (const short8_t*)GtU;
  const int n0 = (cw << 1), n1 = (cw << 1) + 1;
  const int c00 = ((((ks << 3) + n0) << 1) + 0) * 64 + l;
  const int c01 = ((((ks << 3) + n0) << 1) + 1) * 64 + l;
  const int c10 = ((((ks << 3) + n1) << 1) + 0) * 64 + l;
  const int c11 = ((((ks << 3) + n1) << 1) + 1) * 64 + l;

  f32x4 acc00 = {0.f,0.f,0.f,0.f}, acc01 = {0.f,0.f,0.f,0.f};
  f32x4 acc10 = {0.f,0.f,0.f,0.f}, acc11 = {0.f,0.f,0.f,0.f};

  short8_t A0 = G8[(size_t)(j0+0)*4096 + c00], A1 = G8[(size_t)(j0+0)*4096 + c01],
           A2 = G8[(size_t)(j0+0)*4096 + c10], A3 = G8[(size_t)(j0+0)*4096 + c11];
  short8_t Bv0 = G8[(size_t)(j0+1)*4096 + c00], Bv1 = G8[(size_t)(j0+1)*4096 + c01],
           Bv2 = G8[(size_t)(j0+1)*4096 + c10], Bv3 = G8[(size_t)(j0+1)*4096 + c11];
  short8_t C0 = G8[(size_t)(j0+2)*4096 + c00], C1 = G8[(size_t)(j0+2)*4096 + c01],
           C2 = G8[(size_t)(j0+2)*4096 + c10], C3 = G8[(size_t)(j0+2)*4096 + c11];
  short8_t D0 = G8[(size_t)(j0+3)*4096 + c00], D1 = G8[(size_t)(j0+3)*4096 + c01],
           D2 = G8[(size_t)(j0+3)*4096 + c10], D3 = G8[(size_t)(j0+3)*4096 + c11];

  const int jend = j0 + 76;
  for (int jp = j0; jp < jend; jp += 4) {
    const int n4 = (jp + 4 < jend) ? jp + 4 : jend - 1;
    const int n5 = (jp + 5 < jend) ? jp + 5 : jend - 1;
    const int n6 = (jp + 6 < jend) ? jp + 6 : jend - 1;
    const int n7 = (jp + 7 < jend) ? jp + 7 : jend - 1;
    GBODY(jp + 0, A0, A1, A2, A3, n4);
    GBODY(jp + 1, Bv0, Bv1, Bv2, Bv3, n5);
    GBODY(jp + 2, C0, C1, C2, C3, n6);
    GBODY(jp + 3, D0, D1, D2, D3, n7);
  }

  {
    const int jb0 = combo * 19;
    for (int jp = jb0; jp < jb0 + 19; ++jp) {
      const float gb0 = Gb[(jp << 7) + (cw << 5) + lr];
      const float gb1 = Gb[(jp << 7) + (cw << 5) + 16 + lr];
#pragma unroll
      for (int r = 0; r < 4; ++r) {
        const float wv0 = wtile[(rw << 5) + (lg << 2) + r][jp];
        const float wv1 = wtile[(rw << 5) + 16 + (lg << 2) + r][jp];
        acc00[r] += wv0 * gb0; acc01[r] += wv0 * gb1;
        acc10[r] += wv1 * gb0; acc11[r] += wv1 * gb1;
      }
    }
  }

  float* __restrict__ dst = part + (size_t)combo * PART_STRIDE + (((size_t)b0) << 7);
  const int colb = (cw << 5) + lr;
#pragma unroll
  for (int r = 0; r < 4; ++r) {
    const int row0 = (rw << 5) + (lg << 2) + r;
    const int row1 = row0 + 16;
    dst[((size_t)row0 << 7) + colb]      = acc00[r];
    dst[((size_t)row0 << 7) + colb + 16] = acc01[r];
    dst[((size_t)row1 << 7) + colb]      = acc10[r];
    dst[((size_t)row1 << 7) + colb + 16] = acc11[r];
  }
}

// ---------- kernel 3: MFMA heads ----------
// grid 256 = (mb 0..63) x (hg 0..3). Block: rows b0=mb*64, heads hg*4..+4.
// 512 thr = 8 waves: wm = w>>1 (16-row m-tile), wn = w&1 (32-col n-half).
__global__ __launch_bounds__(512, 2)
void heads_kernel(const float* __restrict__ ut, const float* __restrict__ part,
                  const short8_t* __restrict__ WH1P, const float* __restrict__ bh1,
                  const short8_t* __restrict__ WH2P, const float* __restrict__ bh2,
                  const short8_t* __restrict__ WH3P, const float* __restrict__ bh3,
                  const float* __restrict__ Wi, const float* __restrict__ bi,
                  float* __restrict__ out) {
  __shared__ float    zuf[64][156];    // f32 zu (reduce staging + injector)
  __shared__ short8_t zua[2560];       // zu A-frags: [mt4][ks5][spl2][l64]
  __shared__ short8_t g1a[1024];       // g1 A-frags: [mt4][ks2][spl2][l64]
  __shared__ short8_t g2a[1024];       // g2 A-frags: same shape
  const int t  = threadIdx.x;
  const int l  = t & 63;
  const int w  = t >> 6;
  const int wm = w >> 1, wn = w & 1;
  const int mb = blockIdx.x >> 2;
  const int hg = blockIdx.x & 3;
  const int b0 = mb << 6;
  float* __restrict__ zt1_out = out;
  float* __restrict__ yt1_out = out + (size_t)NB * LAT;

  // ---- phase 0: reduce 8 partial slices -> zuf rows; hg0 writes zt1 ----
  for (int idx = t; idx < 2048; idx += 512) {         // 64 rows x 32 float4
    const int r = idx >> 5, c4 = (idx & 31) << 2;
    const size_t off = (((size_t)(b0 + r)) << 7) + c4;
    float4 s = *(const float4*)(part + off);
#pragma unroll
    for (int q = 1; q < 8; ++q) {
      const float4 v = *(const float4*)(part + (size_t)q * PART_STRIDE + off);
      s.x += v.x; s.y += v.y; s.z += v.z; s.w += v.w;
    }
    *(float4*)(&zuf[r][c4]) = s;
    if (hg == 0) *(float4*)(zt1_out + off) = s;
  }
  for (int idx = t; idx < 384; idx += 512) {          // ut -> cols 128..151
    const int r = idx / 6, u4 = (idx - r * 6) << 2;
    *(float4*)(&zuf[r][LAT + u4]) = *(const float4*)(ut + (size_t)(b0 + r) * UD + u4);
  }
  __syncthreads();

  // ---- phase 0.5: zu -> A-fragments (hi/lo bf16), fragment-ordered ----
  for (int c = t; c < 2560; c += 512) {
    const int cl = c & 63;
    const int q  = c >> 6;
    const int spl = q & 1;
    const int q2  = q >> 1;
    const int ks  = q2 % 5;
    const int mt  = q2 / 5;
    const int row = (mt << 4) + (cl & 15);
    const int k0  = (ks << 5) + ((cl >> 4) << 3);
    FragU fr;
#pragma unroll
    for (int j = 0; j < 8; ++j) {
      const int k = k0 + j;
      const float v = (k < ZUD) ? zuf[row][k] : 0.f;
      fr.u[j] = spl ? bf16_lo(v) : bf16_hi(v);
    }
    zua[c] = fr.s;
  }
  __syncthreads();

  // hoist this wave's zu A-frags (head-invariant)
  short8_t Ahi[5], Alo[5];
#pragma unroll
  for (int ks = 0; ks < 5; ++ks) {
    Ahi[ks] = zua[(((wm * 5 + ks) << 1) + 0) * 64 + l];
    Alo[ks] = zua[(((wm * 5 + ks) << 1) + 1) * 64 + l];
  }

  unsigned short* __restrict__ g1s = (unsigned short*)g1a;
  unsigned short* __restrict__ g2s = (unsigned short*)g2a;
  const int lq = l >> 4;   // 0..3

  for (int hc = 0; hc < 4; ++hc) {
    const int hh = (hg << 2) + hc;

    // ---- layer 1: [64x160] x [160x64], 3-product hi/lo ----
    const short8_t* __restrict__ W1 = WH1P + (size_t)hh * 2560;
    short8_t b1h[5][2], b1l[5][2];
#pragma unroll
    for (int ks = 0; ks < 5; ++ks)
#pragma unroll
      for (int nt = 0; nt < 2; ++nt) {
        const int ntg = (wn << 1) + nt;
        b1h[ks][nt] = W1[(((ks << 2) + ntg) * 2 + 0) * 64 + l];
        b1l[ks][nt] = W1[(((ks << 2) + ntg) * 2 + 1) * 64 + l];
      }
    f32x4 a1[2] = {{0.f,0.f,0.f,0.f},{0.f,0.f,0.f,0.f}};
#pragma unroll
    for (int ks = 0; ks < 5; ++ks)
#pragma unroll
      for (int nt = 0; nt < 2; ++nt) {
        a1[nt] = MFMA_BF16(Ahi[ks], b1h[ks][nt], a1[nt]);
        a1[nt] = MFMA_BF16(Alo[ks], b1h[ks][nt], a1[nt]);
        a1[nt] = MFMA_BF16(Ahi[ks], b1l[ks][nt], a1[nt]);
      }
    // bias + relu + write A-frag-ordered g1
#pragma unroll
    for (int nt = 0; nt < 2; ++nt) {
      const int C = (wn << 5) + (nt << 4) + (l & 15);
      const float bv = bh1[(hh << 6) + C];
      const int chunkbase = (((wm << 1) + (C >> 5)) << 1);
      const int lp = (lq << 2) | (((C >> 3) & 3) << 4);   // (R&15 low bits) | k-group
#pragma unroll
      for (int r = 0; r < 4; ++r) {
        const float v = fmaxf(a1[nt][r] + bv, 0.f);
        const int lpr = (lp + r) | (lp & 0x30);           // careful: lp already has k-group
        const int lane2 = ((lq << 2) + r) | ((((C >> 3) & 3)) << 4);
        const int ch_hi = (chunkbase + 0) * 64 + lane2;
        const int ch_lo = (chunkbase + 1) * 64 + lane2;
        g1s[(ch_hi << 3) + (C & 7)] = bf16_hi(v);
        g1s[(ch_lo << 3) + (C & 7)] = bf16_lo(v);
        (void)lpr;
      }
    }
    __syncthreads();

    // ---- layer 2: [64x64] x [64x64] ----
    const short8_t* __restrict__ W2 = WH2P + (size_t)hh * 1024;
    short8_t A2h[2], A2l[2];
#pragma unroll
    for (int ks = 0; ks < 2; ++ks) {
      A2h[ks] = g1a[(((wm << 1) + ks) * 2 + 0) * 64 + l];
      A2l[ks] = g1a[(((wm << 1) + ks) * 2 + 1) * 64 + l];
    }
    f32x4 a2[2] = {{0.f,0.f,0.f,0.f},{0.f,0.f,0.f,0.f}};
#pragma unroll
    for (int ks = 0; ks < 2; ++ks)
#pragma unroll
      for (int nt = 0; nt < 2; ++nt) {
        const int ntg = (wn << 1) + nt;
        const short8_t bh = W2[(((ks << 2) + ntg) * 2 + 0) * 64 + l];
        const short8_t bl = W2[(((ks << 2) + ntg) * 2 + 1) * 64 + l];
        a2[nt] = MFMA_BF16(A2h[ks], bh, a2[nt]);
        a2[nt] = MFMA_BF16(A2l[ks], bh, a2[nt]);
        a2[nt] = MFMA_BF16(A2h[ks], bl, a2[nt]);
      }
#pragma unroll
    for (int nt = 0; nt < 2; ++nt) {
      const int C = (wn << 5) + (nt << 4) + (l & 15);
      const float bv = bh2[(hh << 6) + C];
      const int chunkbase = (((wm << 1) + (C >> 5)) << 1);
#pragma unroll
      for (int r = 0; r < 4; ++r) {
        const float v = fmaxf(a2[nt][r] + bv, 0.f);
        const int lane2 = ((lq << 2) + r) | ((((C >> 3) & 3)) << 4);
        g2s[(((chunkbase + 0) * 64 + lane2) << 3) + (C & 7)] = bf16_hi(v);
        g2s[(((chunkbase + 1) * 64 + lane2) << 3) + (C & 7)] = bf16_lo(v);
      }
    }
    __syncthreads();

    // ---- layer 3: [64x64] x [64x16] (cols 0..1 valid), wn==0 waves only ----
    if (wn == 0) {
      const short8_t* __restrict__ W3 = WH3P + (size_t)hh * 256;
      f32x4 a3 = {0.f,0.f,0.f,0.f};
#pragma unroll
      for (int ks = 0; ks < 2; ++ks) {
        const short8_t Ah = g2a[(((wm << 1) + ks) * 2 + 0) * 64 + l];
        const short8_t Al = g2a[(((wm << 1) + ks) * 2 + 1) * 64 + l];
        const short8_t bh = W3[((ks << 1) + 0) * 64 + l];
        const short8_t bl = W3[((ks << 1) + 1) * 64 + l];
        a3 = MFMA_BF16(Ah, bh, a3);
        a3 = MFMA_BF16(Al, bh, a3);
        a3 = MFMA_BF16(Ah, bl, a3);
      }
      if ((l & 15) < 2) {
        const int col = l & 15;
        const float bv = bh3[(hh << 1) + col];
#pragma unroll
        for (int r = 0; r < 4; ++r) {
          const int R = (wm << 4) + (lq << 2) + r;
          yt1_out[(size_t)(b0 + R) * 40 + (hh << 1) + col] = a3[r] + bv;
        }
      }
    }
  }

  // ---- injector (hg3 blocks): inj = zu @ Wi.T + bi ----
  if (hg == 3) {
    const int r  = t >> 3, io = t & 7;
    const float4* __restrict__ wrow = (const float4*)(Wi + (size_t)io * ZUD);
    const float4* __restrict__ zr   = (const float4*)(&zuf[r][0]);
    float a0 = 0, a1 = 0, a2 = 0, a3 = 0;
#pragma unroll
    for (int cc = 0; cc < 38; ++cc) {
      const float4 wv = wrow[cc];
      const float4 zv = zr[cc];
      a0 = fmaf(wv.x, zv.x, a0); a1 = fmaf(wv.y, zv.y, a1);
      a2 = fmaf(wv.z, zv.z, a2); a3 = fmaf(wv.w, zv.w, a3);
    }
    yt1_out[(size_t)(b0 + r) * 40 + 32 + io] = a0 + a1 + a2 + a3 + bi[io];
  }
}

// ---------------------------------------------------------------------------
extern "C" void kernel_launch(void* const* d_in, const int* in_sizes, int n_in,
                              void* d_out, int out_size, void* d_ws, size_t ws_size,
                              hipStream_t stream) {
  const float* zt  = (const float*)d_in[0];
  const float* dt  = (const float*)d_in[1];
  const float* ut  = (const float*)d_in[2];
  const float* We1 = (const float*)d_in[3];
  const float* be1 = (const float*)d_in[4];
  const float* We2 = (const float*)d_in[5];
  const float* be2 = (const float*)d_in[6];
  const float* We3 = (const float*)d_in[7];
  const float* be3 = (const float*)d_in[8];
  const float* WA  = (const float*)d_in[9];
  const float* bA  = (const float*)d_in[10];
  const float* WB  = (const float*)d_in[11];
  const float* bB  = (const float*)d_in[12];
  const float* Wh1 = (const float*)d_in[13];
  const float* bh1 = (const float*)d_in[14];
  const float* Wh2 = (const float*)d_in[15];
  const float* bh2 = (const float*)d_in[16];
  const float* Wh3 = (const float*)d_in[17];
  const float* bh3 = (const float*)d_in[18];
  const float* Wi  = (const float*)d_in[19];
  const float* bi  = (const float*)d_in[20];

  float* ws = (float*)d_ws;
  unsigned short* GtU = (unsigned short*)(ws + GT_OFF);
  float* Gb   = ws + GB_OFF;
  float* hz   = ws + HZ_OFF;
  float* part = ws + PART_OFF;
  short8_t* WH1P = (short8_t*)(ws + WH1P_OFF);
  short8_t* WH2P = (short8_t*)(ws + WH2P_OFF);
  short8_t* WH3P = (short8_t*)(ws + WH3P_OFF);
  float* out  = (float*)d_out;

  hipLaunchKernelGGL(prep_kernel, dim3(152 + NB / 8 + 16), dim3(256), 0, stream,
                     WA, bA, WB, bB, GtU, Gb,
                     zt, dt, We1, be1, We2, be2, We3, be3, hz,
                     Wh1, Wh2, Wh3, WH1P, WH2P, WH3P);
  hipLaunchKernelGGL(gemm_mfma_kernel, dim3(512), dim3(512), 0, stream,
                     zt, dt, ut, GtU, Gb, hz, part);
  hipLaunchKernelGGL(heads_kernel, dim3(256), dim3(512), 0, stream,
                     ut, part, WH1P, bh1, WH2P, bh2, WH3P, bh3, Wi, bi, out);
}